// Round 1
// baseline (2366.974 us; speedup 1.0000x reference)
//
#include <hip/hip_runtime.h>
#include <hip/hip_bf16.h>

// TensorProductConv: per-edge tensor product + segment-sum scatter.
// X: (V, 4*C) f32, Y: (E, 4) f32, W: (E, 5*C) f32, rows/cols: (E,) int32.
// Z: (V, 11*C) f32.  C = 32.
//
// Output layout per row (11*C = 352):
//   [0,   32)  p00[c]            = w0[c]*xj0[c]*y0
//   [32, 128)  p01[c,k]          = w1[c]*xj0[c]*y1[k]
//   [128,224)  p10[c,k]          = w2[c]*y0*xj1[c,k]
//   [224,256)  p110[c]           = w3[c]*dot(xj1[c,:],y1)/sqrt3
//   [256,352)  p111[c,k]         = w4[c]*cross(xj1[c,:],y1)[k]/sqrt2

#define C 32
#define ZCOLS (11 * C)
#define INV_SQRT3 0.57735026918962576451f
#define INV_SQRT2 0.70710678118654752440f

__global__ void tpconv_kernel(const float* __restrict__ X,
                              const float* __restrict__ Y,
                              const float* __restrict__ W,
                              const int* __restrict__ rows,
                              const int* __restrict__ cols,
                              float* __restrict__ Z,
                              int E) {
    int tid = blockIdx.x * blockDim.x + threadIdx.x;
    int e = tid >> 5;          // one thread per (edge, channel)
    int c = tid & 31;
    if (e >= E) return;

    int row = rows[e];
    int col = cols[e];

    // Y row (4 floats, broadcast across the 32 channel-lanes of this edge)
    const float4 y = *reinterpret_cast<const float4*>(Y + (size_t)e * 4);
    const float y0 = y.x, y1x = y.y, y1y = y.z, y1z = y.w;

    // X gather: x0[c] and x1[c, 0..2]
    const float* Xe = X + (size_t)col * (4 * C);
    const float xj0 = Xe[c];
    const float a0 = Xe[C + 3 * c + 0];
    const float a1 = Xe[C + 3 * c + 1];
    const float a2 = Xe[C + 3 * c + 2];

    // W row: 5 coalesced channel-strided reads
    const float* We = W + (size_t)e * (5 * C);
    const float w0 = We[0 * C + c];
    const float w1 = We[1 * C + c];
    const float w2 = We[2 * C + c];
    const float w3 = We[3 * C + c];
    const float w4 = We[4 * C + c];

    float* Zr = Z + (size_t)row * ZCOLS;

    // p00
    atomicAdd(&Zr[c], w0 * xj0 * y0);

    // p01: (w1*xj0) outer y1
    const float t01 = w1 * xj0;
    atomicAdd(&Zr[C + 3 * c + 0], t01 * y1x);
    atomicAdd(&Zr[C + 3 * c + 1], t01 * y1y);
    atomicAdd(&Zr[C + 3 * c + 2], t01 * y1z);

    // p10: (w2*y0) * xj1
    const float t10 = w2 * y0;
    atomicAdd(&Zr[4 * C + 3 * c + 0], t10 * a0);
    atomicAdd(&Zr[4 * C + 3 * c + 1], t10 * a1);
    atomicAdd(&Zr[4 * C + 3 * c + 2], t10 * a2);

    // p110: w3 * dot(xj1, y1) / sqrt(3)
    const float dot = a0 * y1x + a1 * y1y + a2 * y1z;
    atomicAdd(&Zr[7 * C + c], w3 * dot * INV_SQRT3);

    // p111: w4 * cross(xj1, y1) / sqrt(2)
    const float cx = a1 * y1z - a2 * y1y;
    const float cy = a2 * y1x - a0 * y1z;
    const float cz = a0 * y1y - a1 * y1x;
    const float s = w4 * INV_SQRT2;
    atomicAdd(&Zr[8 * C + 3 * c + 0], s * cx);
    atomicAdd(&Zr[8 * C + 3 * c + 1], s * cy);
    atomicAdd(&Zr[8 * C + 3 * c + 2], s * cz);
}

extern "C" void kernel_launch(void* const* d_in, const int* in_sizes, int n_in,
                              void* d_out, int out_size, void* d_ws, size_t ws_size,
                              hipStream_t stream) {
    const float* X    = (const float*)d_in[0];
    const float* Y    = (const float*)d_in[1];
    const float* W    = (const float*)d_in[2];
    const int*   rows = (const int*)d_in[3];
    const int*   cols = (const int*)d_in[4];
    float*       Z    = (float*)d_out;

    const int E = in_sizes[1] / 4;  // Y is (E, 4)

    // Harness poisons d_out with 0xAA and does not re-poison between replays:
    // we must zero it ourselves every call (graph-capturable async memset).
    hipMemsetAsync(d_out, 0, (size_t)out_size * sizeof(float), stream);

    const int threads = 256;
    const long long total = (long long)E * C;
    const int blocks = (int)((total + threads - 1) / threads);
    tpconv_kernel<<<blocks, threads, 0, stream>>>(X, Y, W, rows, cols, Z, E);
}

// Round 2
// 223.162 us; speedup vs baseline: 10.6065x; 10.6065x over previous
//
#include <hip/hip_runtime.h>
#include <hip/hip_bf16.h>

// TensorProductConv, round 2: bucket edges by destination row (no sort needed),
// then one WAVE per output row accumulates in registers and writes each Z
// element exactly once. Eliminates the 281.6M-atomicAdd scatter that made R1
// write 2.9 GB to HBM (vs 70 MB ideal).
//
// X: (V, 4*C) f32, Y: (E, 4) f32, W: (E, 5*C) f32, rows/cols: (E,) int32.
// Z: (V, 11*C) f32.  C = 32, V = 50000, E = 800000 (avg degree 16).

#define C 32
#define ZCOLS (11 * C)
#define MAXDEG 64          // Poisson(16): P(deg > 64) ~ 1e-18 per row; overflow list backs this up
#define OVF_MAX 65536
#define INV_SQRT3 0.57735026918962576451f
#define INV_SQRT2 0.70710678118654752440f

// ---------------- phase 1: bucket edges by destination row ----------------
__global__ void hist_scatter(const int* __restrict__ rows,
                             int* __restrict__ cnt,
                             int* __restrict__ bucket,
                             int* __restrict__ ovf_cnt,
                             int* __restrict__ ovf_list,
                             int E) {
    int e = blockIdx.x * blockDim.x + threadIdx.x;
    if (e >= E) return;
    int r = rows[e];
    int k = atomicAdd(&cnt[r], 1);
    if (k < MAXDEG) {
        bucket[(size_t)r * MAXDEG + k] = e;
    } else {
        int o = atomicAdd(ovf_cnt, 1);
        if (o < OVF_MAX) ovf_list[o] = e;
    }
}

// ---------------- phase 2: one wave per row, register accumulation ----------------
__global__ void tpconv_rows(const float* __restrict__ X,
                            const float* __restrict__ Y,
                            const float* __restrict__ W,
                            const int* __restrict__ cols,
                            const int* __restrict__ cnt,
                            const int* __restrict__ bucket,
                            float* __restrict__ Z,
                            int V) {
    int wid  = blockIdx.x * (blockDim.x >> 6) + (threadIdx.x >> 6);
    int lane = threadIdx.x & 63;
    if (wid >= V) return;
    const int c = lane & 31;   // channel owned by this lane
    const int h = lane >> 5;   // half-wave: h=0 takes even edges, h=1 odd edges

    int n = cnt[wid];
    if (n > MAXDEG) n = MAXDEG;

    float acc[11];
#pragma unroll
    for (int j = 0; j < 11; ++j) acc[j] = 0.0f;

    const int* bkt = bucket + (size_t)wid * MAXDEG;
    for (int i = h; i < n; i += 2) {
        const int e = bkt[i];
        const float4 y = *reinterpret_cast<const float4*>(Y + (size_t)e * 4);
        const int col = cols[e];

        const float* Xe = X + (size_t)col * (4 * C);
        const float xj0 = Xe[c];
        const float a0  = Xe[C + 3 * c + 0];
        const float a1  = Xe[C + 3 * c + 1];
        const float a2  = Xe[C + 3 * c + 2];

        const float* We = W + (size_t)e * (5 * C);
        const float w0 = We[0 * C + c];
        const float w1 = We[1 * C + c];
        const float w2 = We[2 * C + c];
        const float w3 = We[3 * C + c];
        const float w4 = We[4 * C + c];

        acc[0] += w0 * xj0 * y.x;

        const float t01 = w1 * xj0;
        acc[1] += t01 * y.y;
        acc[2] += t01 * y.z;
        acc[3] += t01 * y.w;

        const float t10 = w2 * y.x;
        acc[4] += t10 * a0;
        acc[5] += t10 * a1;
        acc[6] += t10 * a2;

        acc[7] += w3 * (a0 * y.y + a1 * y.z + a2 * y.w) * INV_SQRT3;

        const float s = w4 * INV_SQRT2;
        acc[8]  += s * (a1 * y.w - a2 * y.z);
        acc[9]  += s * (a2 * y.y - a0 * y.w);
        acc[10] += s * (a0 * y.z - a1 * y.y);
    }

    // combine the two half-wave partial sums
#pragma unroll
    for (int j = 0; j < 11; ++j) acc[j] += __shfl_xor(acc[j], 32);

    if (h == 0) {
        float* Zr = Z + (size_t)wid * ZCOLS;
        Zr[c]               = acc[0];
        Zr[C + 3 * c + 0]   = acc[1];
        Zr[C + 3 * c + 1]   = acc[2];
        Zr[C + 3 * c + 2]   = acc[3];
        Zr[4 * C + 3 * c + 0] = acc[4];
        Zr[4 * C + 3 * c + 1] = acc[5];
        Zr[4 * C + 3 * c + 2] = acc[6];
        Zr[7 * C + c]       = acc[7];
        Zr[8 * C + 3 * c + 0] = acc[8];
        Zr[8 * C + 3 * c + 1] = acc[9];
        Zr[8 * C + 3 * c + 2] = acc[10];
    }
}

// ---------------- phase 3: rare-overflow fallback (normally 0 edges) ----------------
__global__ void ovf_apply(const float* __restrict__ X,
                          const float* __restrict__ Y,
                          const float* __restrict__ W,
                          const int* __restrict__ rows,
                          const int* __restrict__ cols,
                          const int* __restrict__ ovf_cnt,
                          const int* __restrict__ ovf_list,
                          float* __restrict__ Z) {
    int no = *ovf_cnt;
    if (no > OVF_MAX) no = OVF_MAX;
    int total = no * C;
    for (int t = blockIdx.x * blockDim.x + threadIdx.x; t < total;
         t += gridDim.x * blockDim.x) {
        const int i = t >> 5, c = t & 31;
        const int e = ovf_list[i];
        const float4 y = *reinterpret_cast<const float4*>(Y + (size_t)e * 4);
        const int row = rows[e];
        const int col = cols[e];
        const float* Xe = X + (size_t)col * (4 * C);
        const float xj0 = Xe[c];
        const float a0  = Xe[C + 3 * c + 0];
        const float a1  = Xe[C + 3 * c + 1];
        const float a2  = Xe[C + 3 * c + 2];
        const float* We = W + (size_t)e * (5 * C);
        const float w0 = We[c], w1 = We[C + c], w2 = We[2 * C + c],
                    w3 = We[3 * C + c], w4 = We[4 * C + c];
        float* Zr = Z + (size_t)row * ZCOLS;
        atomicAdd(&Zr[c], w0 * xj0 * y.x);
        const float t01 = w1 * xj0;
        atomicAdd(&Zr[C + 3 * c + 0], t01 * y.y);
        atomicAdd(&Zr[C + 3 * c + 1], t01 * y.z);
        atomicAdd(&Zr[C + 3 * c + 2], t01 * y.w);
        const float t10 = w2 * y.x;
        atomicAdd(&Zr[4 * C + 3 * c + 0], t10 * a0);
        atomicAdd(&Zr[4 * C + 3 * c + 1], t10 * a1);
        atomicAdd(&Zr[4 * C + 3 * c + 2], t10 * a2);
        atomicAdd(&Zr[7 * C + c], w3 * (a0 * y.y + a1 * y.z + a2 * y.w) * INV_SQRT3);
        const float s = w4 * INV_SQRT2;
        atomicAdd(&Zr[8 * C + 3 * c + 0], s * (a1 * y.w - a2 * y.z));
        atomicAdd(&Zr[8 * C + 3 * c + 1], s * (a2 * y.y - a0 * y.w));
        atomicAdd(&Zr[8 * C + 3 * c + 2], s * (a0 * y.z - a1 * y.y));
    }
}

extern "C" void kernel_launch(void* const* d_in, const int* in_sizes, int n_in,
                              void* d_out, int out_size, void* d_ws, size_t ws_size,
                              hipStream_t stream) {
    const float* X    = (const float*)d_in[0];
    const float* Y    = (const float*)d_in[1];
    const float* W    = (const float*)d_in[2];
    const int*   rows = (const int*)d_in[3];
    const int*   cols = (const int*)d_in[4];
    float*       Z    = (float*)d_out;

    const int E = in_sizes[1] / 4;        // Y is (E, 4)
    const int V = in_sizes[0] / (4 * C);  // X is (V, 4*C)

    // workspace layout: [cnt: V][ovf_cnt: 1][ovf_list: OVF_MAX][bucket: V*MAXDEG]
    int* cnt      = (int*)d_ws;
    int* ovf_cnt  = cnt + V;
    int* ovf_list = ovf_cnt + 1;
    int* bucket   = ovf_list + OVF_MAX;

    // zero counters (cnt + ovf_cnt contiguous)
    hipMemsetAsync(cnt, 0, (size_t)(V + 1) * sizeof(int), stream);

    {
        const int threads = 256;
        const int blocks = (E + threads - 1) / threads;
        hist_scatter<<<blocks, threads, 0, stream>>>(rows, cnt, bucket, ovf_cnt,
                                                     ovf_list, E);
    }
    {
        const int threads = 256;                  // 4 waves/block
        const int wavesPerBlock = threads / 64;
        const int blocks = (V + wavesPerBlock - 1) / wavesPerBlock;
        tpconv_rows<<<blocks, threads, 0, stream>>>(X, Y, W, cols, cnt, bucket, Z, V);
    }
    {
        ovf_apply<<<64, 256, 0, stream>>>(X, Y, W, rows, cols, ovf_cnt, ovf_list, Z);
    }
}